// Round 2
// baseline (224.724 us; speedup 1.0000x reference)
//
#include <hip/hip_runtime.h>

// GINDecor on MI355X. All inputs/outputs are FLOAT32 (per reference setup_inputs).
// Algebraic collapse: no nonlinearity after the edge gate, so
//   M = W1@W2 (256x2), cz = b1@W2, y = x@M,
//   z = An@y + r*y + cz,  result = An@z + r*z + b2.
// A = adj*gate + I with gate_ij = f(deg_row[i], deg_col[j]) only at edges
// (feats at an edge are [1, deg_row[i], deg_col[j]]; softmax over 2 logits
//  collapses to sigmoid of the logit difference).

typedef unsigned int u32;

#define N_NODES 4096
#define MAX_DEG 128   // mean deg ~41, sd ~6.4; 128 is >13 sigma

// ---- tiny precompute: gate coefficients, M = W1@W2, cz = b1@W2, cfin = b2 ----
__global__ void k_small(const float* __restrict__ We1, const float* __restrict__ be1,
                        const float* __restrict__ We2, const float* __restrict__ be2,
                        const float* __restrict__ W1,  const float* __restrict__ b1,
                        const float* __restrict__ W2,  const float* __restrict__ b2,
                        float* __restrict__ M, float* __restrict__ coef,
                        float* __restrict__ cz, float* __restrict__ cfin) {
    int gid = blockIdx.x * 256 + threadIdx.x;
    if (gid < 512) {                       // M[t*2+d] = sum_h W1[t,h] * W2[h,d]
        int t = gid >> 1, d = gid & 1;
        float s = 0.f;
        for (int h = 0; h < 128; ++h)
            s = fmaf(W1[t * 128 + h], W2[h * 2 + d], s);
        M[gid] = s;
    } else if (gid < 528) {                // gate-MLP coefficients (adj==1 folded)
        int w = gid - 512;
        coef[w * 4 + 0] = We1[w] + be1[w];             // We1[0,w]*1 + be1[w]
        coef[w * 4 + 1] = We1[16 + w];                 // We1[1,w] (xdeg weight)
        coef[w * 4 + 2] = We1[32 + w];                 // We1[2,w] (ydeg weight)
        coef[w * 4 + 3] = We2[w * 2 + 1] - We2[w * 2]; // logit-diff weight
    } else if (gid == 528) {
        coef[64] = be2[1] - be2[0];
    } else if (gid < 531) {                // cz[d] = sum_h b1[h] * W2[h,d]
        int d = gid - 529;
        float s = 0.f;
        for (int h = 0; h < 128; ++h)
            s = fmaf(b1[h], W2[h * 2 + d], s);
        cz[d] = s;
    } else if (gid < 533) {
        cfin[gid - 531] = b2[gid - 531];
    }
}

// ---- gate pass: scan adj once, build per-row compacted edge lists ----
__global__ __launch_bounds__(256)
void k_gate(const float* __restrict__ adj, const float* __restrict__ xdeg,
            const float* __restrict__ ydeg, const float* __restrict__ coef,
            int* __restrict__ idx_g, float* __restrict__ w_g,
            float* __restrict__ rs, float* __restrict__ cs, int* __restrict__ cnt) {
    __shared__ float s_coef[65];
    __shared__ int   s_cnt;
    __shared__ float s_rs;
    const int i   = blockIdx.x;
    const int tid = threadIdx.x;
    if (tid < 65) s_coef[tid] = coef[tid];
    if (tid == 0) { s_cnt = 0; s_rs = 0.f; }
    __syncthreads();

    const float dr = xdeg[(size_t)i * N_NODES];   // deg_row[i] (broadcast, col 0)
    const float* arow = adj + (size_t)i * N_NODES;
    int*   idxr = idx_g + (size_t)i * MAX_DEG;
    float* wr   = w_g   + (size_t)i * MAX_DEG;
    float  lrs  = 0.f;

    #pragma unroll
    for (int c = 0; c < 4; ++c) {          // 4 x float4 loads: 16 floats/thread
        int j0 = c * 1024 + tid * 4;
        float4 v = *reinterpret_cast<const float4*>(arow + j0);
        float vals[4] = {v.x, v.y, v.z, v.w};
        #pragma unroll
        for (int q = 0; q < 4; ++q) {
            if (vals[q] != 0.f) {          // adj entry is exactly 1.0 here
                int j = j0 + q;
                float dc = ydeg[j];        // deg_col[j] (broadcast, row 0)
                float delta = s_coef[64];
                #pragma unroll
                for (int w = 0; w < 16; ++w) {
                    float hh = fmaf(s_coef[w * 4 + 2], dc,
                               fmaf(s_coef[w * 4 + 1], dr, s_coef[w * 4 + 0]));
                    hh = fmaxf(hh, 0.f);
                    delta = fmaf(hh, s_coef[w * 4 + 3], delta);
                }
                float gate = 1.f / (1.f + __expf(-delta));  // softmax[...,1]
                lrs += gate;
                atomicAdd(cs + j, gate);
                int pos = atomicAdd(&s_cnt, 1);
                if (pos < MAX_DEG) { idxr[pos] = j; wr[pos] = gate; }
            }
        }
    }
    if (lrs != 0.f) atomicAdd(&s_rs, lrs);
    __syncthreads();
    if (tid == 0) {
        rs[i]  = 1.f + s_rs;               // + self loop
        cnt[i] = (s_cnt < MAX_DEG) ? s_cnt : MAX_DEG;
    }
}

// ---- degree normalization ----
__global__ void k_norm(const float* __restrict__ rs, const float* __restrict__ cs,
                       float* __restrict__ drow, float* __restrict__ dcol) {
    int i = blockIdx.x * 256 + threadIdx.x;
    float r = rs[i];
    drow[i] = (r > 0.f) ? (1.f / sqrtf(r)) : 0.f;
    float c = cs[i] + 1.f;                 // + self loop
    dcol[i] = (c > 0.f) ? (1.f / sqrtf(c)) : 0.f;
}

// ---- y = x @ M  (one block per row, block reduction) ----
__global__ __launch_bounds__(256)
void k_y(const float* __restrict__ x, const float* __restrict__ M, float* __restrict__ y) {
    __shared__ float s0[4], s1[4];
    int i = blockIdx.x, t = threadIdx.x;
    float xv = x[(size_t)i * 256 + t];
    float p0 = xv * M[t * 2];
    float p1 = xv * M[t * 2 + 1];
    #pragma unroll
    for (int o = 32; o > 0; o >>= 1) {
        p0 += __shfl_down(p0, o);
        p1 += __shfl_down(p1, o);
    }
    if ((t & 63) == 0) { s0[t >> 6] = p0; s1[t >> 6] = p1; }
    __syncthreads();
    if (t == 0) {
        y[i * 2 + 0] = s0[0] + s0[1] + s0[2] + s0[3];
        y[i * 2 + 1] = s1[0] + s1[1] + s1[2] + s1[3];
    }
}

// ---- SpMV with 2 columns: vout = drow.*(A_gate@ (dcol.*vin)) + drow*dcol*vin_i
//      + r*vin + add ----
template <bool FINAL>
__global__ __launch_bounds__(256)
void k_spmv(const int* __restrict__ idx_g, const float* __restrict__ w_g,
            const int* __restrict__ cnt, const float* __restrict__ drow,
            const float* __restrict__ dcol, const float* __restrict__ vin,
            const float* __restrict__ addv, const float* __restrict__ rw,
            float* __restrict__ vout) {
    int wv = threadIdx.x >> 6, lane = threadIdx.x & 63;
    int i = blockIdx.x * 4 + wv;
    int nnz = cnt[i];
    const int*   ip = idx_g + (size_t)i * MAX_DEG;
    const float* wp = w_g   + (size_t)i * MAX_DEG;
    float a0 = 0.f, a1 = 0.f;
    for (int k = lane; k < nnz; k += 64) {
        int j = ip[k];
        float wt = wp[k] * dcol[j];
        a0 = fmaf(wt, vin[j * 2 + 0], a0);
        a1 = fmaf(wt, vin[j * 2 + 1], a1);
    }
    #pragma unroll
    for (int o = 32; o > 0; o >>= 1) {
        a0 += __shfl_down(a0, o);
        a1 += __shfl_down(a1, o);
    }
    if (lane == 0) {
        float r  = rw[0];
        float di = drow[i], ci = dcol[i];
        float y0 = vin[i * 2 + 0], y1 = vin[i * 2 + 1];
        float v0 = di * (a0 + ci * y0) + r * y0 + addv[0];
        float v1 = di * (a1 + ci * y1) + r * y1 + addv[1];
        vout[i * 2 + 0] = v0;
        vout[i * 2 + 1] = v1;
    }
}

extern "C" void kernel_launch(void* const* d_in, const int* in_sizes, int n_in,
                              void* d_out, int out_size, void* d_ws, size_t ws_size,
                              hipStream_t stream) {
    const float* x    = (const float*)d_in[0];
    const float* adj  = (const float*)d_in[1];
    const float* xdeg = (const float*)d_in[2];
    const float* ydeg = (const float*)d_in[3];
    const float* We1  = (const float*)d_in[4];
    const float* be1  = (const float*)d_in[5];
    const float* We2  = (const float*)d_in[6];
    const float* be2  = (const float*)d_in[7];
    const float* W1   = (const float*)d_in[8];
    const float* b1   = (const float*)d_in[9];
    const float* W2   = (const float*)d_in[10];
    const float* b2   = (const float*)d_in[11];
    const float* rw   = (const float*)d_in[12];

    char* ws = (char*)d_ws;
    int*   idx_g = (int*)  (ws + 0);         // 4096*128*4 = 2 MB
    float* w_g   = (float*)(ws + 2097152);   // 2 MB
    float* rs    = (float*)(ws + 4194304);   // 16 KB
    float* cs    = (float*)(ws + 4210688);   // 16 KB
    int*   cnt   = (int*)  (ws + 4227072);   // 16 KB
    float* drow  = (float*)(ws + 4243456);   // 16 KB
    float* dcol  = (float*)(ws + 4259840);   // 16 KB
    float* y     = (float*)(ws + 4276224);   // 32 KB
    float* z     = (float*)(ws + 4308992);   // 32 KB
    float* M     = (float*)(ws + 4341760);   // 2 KB
    float* coef  = (float*)(ws + 4343808);   // 65 floats (padded)
    float* cz    = (float*)(ws + 4344320);   // 2 floats
    float* cfin  = (float*)(ws + 4344328);   // 2 floats

    hipMemsetAsync(cs, 0, N_NODES * sizeof(float), stream);
    k_small<<<3, 256, 0, stream>>>(We1, be1, We2, be2, W1, b1, W2, b2, M, coef, cz, cfin);
    k_gate<<<N_NODES, 256, 0, stream>>>(adj, xdeg, ydeg, coef, idx_g, w_g, rs, cs, cnt);
    k_norm<<<N_NODES / 256, 256, 0, stream>>>(rs, cs, drow, dcol);
    k_y<<<N_NODES, 256, 0, stream>>>(x, M, y);
    k_spmv<false><<<N_NODES / 4, 256, 0, stream>>>(idx_g, w_g, cnt, drow, dcol, y, cz, rw, z);
    k_spmv<true><<<N_NODES / 4, 256, 0, stream>>>(idx_g, w_g, cnt, drow, dcol, z, cfin, rw, (float*)d_out);
}

// Round 3
// 209.734 us; speedup vs baseline: 1.0715x; 1.0715x over previous
//
#include <hip/hip_runtime.h>

// GINDecor on MI355X (f32 problem). Algebraic collapse:
//   gate(i,j) = sigmoid(MLP(deg_row[i], deg_col[j])) -- depends ONLY on the two
//   integer degrees => precompute a 128x128 LUT once (degrees are exact small ints).
//   No nonlinearity after the gate, so with M = W1@W2 (256x2), cz = b1@W2:
//     y = x@M,  z = An@y + r*y + cz,  out = An@z + r*z + b2,
//   where An = drow .* (adj*gate + I) .* dcol, drow=rsqrt(rowsum), dcol=rsqrt(colsum).
// 4 dispatches: prep (LUT/M/cz/b2/dc_u8/cs=0) -> gate+y scan -> spmv -> spmv.

typedef unsigned char u8;

#define N_NODES 4096
#define MAX_DEG 128   // mean deg ~41, sd ~6.4; 128 is >13 sigma
#define LUTD    128

// ---- prep: gate LUT, M = W1@W2, cz = b1@W2, cfin = b2, dc_u8, zero cs ----
__global__ __launch_bounds__(256)
void k_prep(const float* __restrict__ We1, const float* __restrict__ be1,
            const float* __restrict__ We2, const float* __restrict__ be2,
            const float* __restrict__ W1,  const float* __restrict__ b1,
            const float* __restrict__ W2,  const float* __restrict__ b2,
            const float* __restrict__ ydeg,
            float* __restrict__ lut, float* __restrict__ M,
            float* __restrict__ cz, float* __restrict__ cfin,
            u8* __restrict__ dc_u8, float* __restrict__ cs) {
    int b = blockIdx.x, tid = threadIdx.x;
    if (b < 64) {                          // gate LUT over (deg_row, deg_col)
        int e = b * 256 + tid;             // 0..16383
        float dr = (float)(e >> 7), dc = (float)(e & 127);
        float delta = be2[1] - be2[0];
        #pragma unroll
        for (int w = 0; w < 16; ++w) {
            float hh = fmaf(We1[32 + w], dc,
                       fmaf(We1[16 + w], dr, We1[w] + be1[w]));
            hh = fmaxf(hh, 0.f);
            delta = fmaf(hh, We2[w * 2 + 1] - We2[w * 2], delta);
        }
        lut[e] = 1.f / (1.f + __expf(-delta));   // softmax[...,1]
    } else if (b < 66) {                   // M[t*2+d] = sum_h W1[t,h]*W2[h,d]
        int e = (b - 64) * 256 + tid;      // 0..511
        int t = e >> 1, d = e & 1;
        float s = 0.f;
        for (int h = 0; h < 128; ++h)
            s = fmaf(W1[t * 128 + h], W2[h * 2 + d], s);
        M[e] = s;
    } else if (b == 66) {
        if (tid < 2) {
            float s = 0.f;
            for (int h = 0; h < 128; ++h)
                s = fmaf(b1[h], W2[h * 2 + tid], s);
            cz[tid]   = s;
            cfin[tid] = b2[tid];
        }
    } else {                               // dc_u8 table + zero cs
        int j = (b - 67) * 256 + tid;      // 0..4095
        int d = (int)ydeg[j];              // row 0 of ydeg = deg_col broadcast
        dc_u8[j] = (u8)(d > 127 ? 127 : d);
        cs[j] = 0.f;
    }
}

// ---- gate scan (per row) fused with y = x@M row reduction ----
__global__ __launch_bounds__(256)
void k_gatey(const float* __restrict__ adj, const float* __restrict__ xdeg,
             const float* __restrict__ x, const float* __restrict__ lut,
             const u8* __restrict__ dc_u8, const float* __restrict__ M,
             int2* __restrict__ e_g, float* __restrict__ rs,
             float* __restrict__ cs, int* __restrict__ cnt,
             float* __restrict__ y) {
    __shared__ float g_row[LUTD];
    __shared__ int   s_cnt;
    __shared__ float s_rs[4], s_y0[4], s_y1[4];
    const int i = blockIdx.x, tid = threadIdx.x;
    const int wv = tid >> 6, lane = tid & 63;
    if (tid == 0) s_cnt = 0;
    if (tid < LUTD) {
        int dri = (int)xdeg[(size_t)i * N_NODES];   // deg_row[i] (broadcast col 0)
        if (dri > 127) dri = 127;
        g_row[tid] = lut[dri * LUTD + tid];
    }
    // y reduction (independent of gates)
    float xv = x[(size_t)i * 256 + tid];
    float p0 = xv * M[tid * 2], p1 = xv * M[tid * 2 + 1];
    #pragma unroll
    for (int o = 32; o > 0; o >>= 1) {
        p0 += __shfl_down(p0, o);
        p1 += __shfl_down(p1, o);
    }
    if (lane == 0) { s_y0[wv] = p0; s_y1[wv] = p1; }
    __syncthreads();

    const float* arow = adj + (size_t)i * N_NODES;
    int2* er = e_g + (size_t)i * MAX_DEG;
    float lrs = 0.f;
    #pragma unroll
    for (int c = 0; c < 4; ++c) {          // 4 x float4: 16 candidates/thread
        int j0 = c * 1024 + tid * 4;
        float4 v = *reinterpret_cast<const float4*>(arow + j0);
        float vals[4] = {v.x, v.y, v.z, v.w};
        #pragma unroll
        for (int q = 0; q < 4; ++q) {
            if (vals[q] != 0.f) {
                int j = j0 + q;
                float gate = g_row[dc_u8[j]];
                lrs += gate;
                atomicAdd(cs + j, gate);
                int pos = atomicAdd(&s_cnt, 1);
                if (pos < MAX_DEG) er[pos] = make_int2(j, __float_as_int(gate));
            }
        }
    }
    #pragma unroll
    for (int o = 32; o > 0; o >>= 1) lrs += __shfl_down(lrs, o);
    if (lane == 0) s_rs[wv] = lrs;
    __syncthreads();
    if (tid == 0) {
        rs[i]  = 1.f + s_rs[0] + s_rs[1] + s_rs[2] + s_rs[3];  // + self loop
        cnt[i] = (s_cnt < MAX_DEG) ? s_cnt : MAX_DEG;
        y[i * 2 + 0] = s_y0[0] + s_y0[1] + s_y0[2] + s_y0[3];
        y[i * 2 + 1] = s_y1[0] + s_y1[1] + s_y1[2] + s_y1[3];
    }
}

// ---- 2-column SpMV: vout = drow.*(Agate@(dcol.*vin) + dcol_i*vin_i) + r*vin + add
//      drow/dcol computed inline from rs/cs (rs>=1, cs+1>=1 always). ----
__global__ __launch_bounds__(256)
void k_spmv(const int2* __restrict__ e_g, const int* __restrict__ cnt,
            const float* __restrict__ rs, const float* __restrict__ cs,
            const float* __restrict__ vin, const float* __restrict__ addv,
            const float* __restrict__ rw, float* __restrict__ vout) {
    int wv = threadIdx.x >> 6, lane = threadIdx.x & 63;
    int i = blockIdx.x * 4 + wv;
    int nnz = cnt[i];
    const int2* ep = e_g + (size_t)i * MAX_DEG;
    float a0 = 0.f, a1 = 0.f;
    for (int k = lane; k < nnz; k += 64) {
        int2 e = ep[k];
        int j = e.x;
        float wt = __int_as_float(e.y) * rsqrtf(cs[j] + 1.f);
        a0 = fmaf(wt, vin[j * 2 + 0], a0);
        a1 = fmaf(wt, vin[j * 2 + 1], a1);
    }
    #pragma unroll
    for (int o = 32; o > 0; o >>= 1) {
        a0 += __shfl_down(a0, o);
        a1 += __shfl_down(a1, o);
    }
    if (lane == 0) {
        float r  = rw[0];
        float di = rsqrtf(rs[i]), ci = rsqrtf(cs[i] + 1.f);
        float y0 = vin[i * 2 + 0], y1 = vin[i * 2 + 1];
        vout[i * 2 + 0] = di * (a0 + ci * y0) + r * y0 + addv[0];
        vout[i * 2 + 1] = di * (a1 + ci * y1) + r * y1 + addv[1];
    }
}

extern "C" void kernel_launch(void* const* d_in, const int* in_sizes, int n_in,
                              void* d_out, int out_size, void* d_ws, size_t ws_size,
                              hipStream_t stream) {
    const float* x    = (const float*)d_in[0];
    const float* adj  = (const float*)d_in[1];
    const float* xdeg = (const float*)d_in[2];
    const float* ydeg = (const float*)d_in[3];
    const float* We1  = (const float*)d_in[4];
    const float* be1  = (const float*)d_in[5];
    const float* We2  = (const float*)d_in[6];
    const float* be2  = (const float*)d_in[7];
    const float* W1   = (const float*)d_in[8];
    const float* b1   = (const float*)d_in[9];
    const float* W2   = (const float*)d_in[10];
    const float* b2   = (const float*)d_in[11];
    const float* rw   = (const float*)d_in[12];

    char* ws = (char*)d_ws;
    int2*  e_g  = (int2*) (ws + 0);          // 4096*128*8 = 4 MB
    float* lut  = (float*)(ws + 4194304);    // 64 KB
    float* rs   = (float*)(ws + 4259840);    // 16 KB
    float* cs   = (float*)(ws + 4276224);    // 16 KB
    int*   cnt  = (int*)  (ws + 4292608);    // 16 KB
    float* y    = (float*)(ws + 4308992);    // 32 KB
    float* z    = (float*)(ws + 4341760);    // 32 KB
    float* M    = (float*)(ws + 4374528);    // 2 KB
    float* cz   = (float*)(ws + 4376576);    // 8 B
    float* cfin = (float*)(ws + 4376584);    // 8 B
    u8*    dcu  = (u8*)   (ws + 4376592);    // 4 KB

    k_prep<<<83, 256, 0, stream>>>(We1, be1, We2, be2, W1, b1, W2, b2, ydeg,
                                   lut, M, cz, cfin, dcu, cs);
    k_gatey<<<N_NODES, 256, 0, stream>>>(adj, xdeg, x, lut, dcu, M,
                                         e_g, rs, cs, cnt, y);
    k_spmv<<<N_NODES / 4, 256, 0, stream>>>(e_g, cnt, rs, cs, y, cz, rw, z);
    k_spmv<<<N_NODES / 4, 256, 0, stream>>>(e_g, cnt, rs, cs, z, cfin, rw, (float*)d_out);
}